// Round 17
// baseline (4674.475 us; speedup 1.0000x reference)
//
#include <hip/hip_runtime.h>
#include <math.h>

#define BB 256
#define TT 512
#define DD 256
#define HH 512
#define SS 8
#define G4H 2048
#define BH (BB*HH)          // 131072
#define OUT_BASE ((size_t)BB*TT*DD)
#define NGRP 16
#define GR 16               // batch rows per group
#define XSLOT_U32 4096      // 16 KB per group-slot: 16 rows x 256 u32 (fp16 pairs)
#define FSTRIDE 16          // ints between flags (64 B): one cache line per flag

typedef _Float16 f16;
typedef __attribute__((ext_vector_type(8))) _Float16 f16x8;
typedef __attribute__((ext_vector_type(4))) float    f32x4;

__device__ __forceinline__ float sigm(float x) { return 1.f / (1.f + __expf(-x)); }
__device__ __forceinline__ float ftanh(float x) {
  x = fminf(15.f, fmaxf(-15.f, x));
  float e = __expf(-2.f * x);
  return (1.f - e) / (1.f + e);
}

// ---------------- prep kernels ----------------

__global__ __launch_bounds__(256) void prep_wbig16(
    const float* __restrict__ W_ih, const float* __restrict__ W_hh,
    const float* __restrict__ W_lin, f16* __restrict__ Wbig16)
{
  __shared__ float As[64][20];
  __shared__ float Bs[16][68];
  const int n0 = blockIdx.x * 64;
  const int j0 = blockIdx.y * 64;
  const int tid = threadIdx.x;
  const int tn = tid >> 4, tj = tid & 15;
  float acc[4][4] = {};
  for (int k0 = 0; k0 < DD; k0 += 16) {
    { int r = tid >> 2, c = (tid & 3) * 4;
      *(float4*)&As[r][c] = *(const float4*)&W_ih[(size_t)(n0 + r) * DD + k0 + c]; }
    { int r = tid >> 4, c = (tid & 15) * 4;
      *(float4*)&Bs[r][c] = *(const float4*)&W_lin[(size_t)(k0 + r) * HH + j0 + c]; }
    __syncthreads();
    #pragma unroll
    for (int k = 0; k < 16; ++k) {
      float a[4], bv[4];
      #pragma unroll
      for (int i = 0; i < 4; ++i) a[i] = As[tn*4+i][k];
      #pragma unroll
      for (int m = 0; m < 4; ++m) bv[m] = Bs[k][tj*4+m];
      #pragma unroll
      for (int i = 0; i < 4; ++i)
        #pragma unroll
        for (int m = 0; m < 4; ++m)
          acc[i][m] = fmaf(a[i], bv[m], acc[i][m]);
    }
    __syncthreads();
  }
  #pragma unroll
  for (int i = 0; i < 4; ++i) {
    int n = n0 + tn*4 + i;
    #pragma unroll
    for (int m = 0; m < 4; ++m) {
      int j = j0 + tj*4 + m;
      Wbig16[(size_t)n*HH + j] = (f16)(acc[i][m] + W_hh[(size_t)n*HH + j]);
    }
  }
}

__global__ void prep_bias(const float* __restrict__ b_ih, const float* __restrict__ b_hh,
                          const float* __restrict__ W_ih, const float* __restrict__ b_lin,
                          float* __restrict__ bias0, float* __restrict__ bias1)
{
  int n = blockIdx.x * 256 + threadIdx.x;   // grid 8
  float s = b_ih[n] + b_hh[n];
  float d = 0.f;
  for (int k = 0; k < DD; ++k) d = fmaf(W_ih[(size_t)n*DD + k], b_lin[k], d);
  bias0[n] = s;
  bias1[n] = s + d;
}

#define NIH (G4H*DD)
#define NHH (G4H*HH)
__global__ void prep_cvtw(const float* __restrict__ W_ih, const float* __restrict__ W_hh,
                          const float* __restrict__ W_lin,
                          f16* __restrict__ Wih16, f16* __restrict__ Whh16,
                          f16* __restrict__ Wlin16)
{
  int e = blockIdx.x * 256 + threadIdx.x;   // grid 6656
  if (e < NIH) Wih16[e] = (f16)W_ih[e];
  else if (e < NIH + NHH) Whh16[e - NIH] = (f16)W_hh[e - NIH];
  else Wlin16[e - NIH - NHH] = (f16)W_lin[e - NIH - NHH];
}

__global__ void prep_init(const float* __restrict__ x0, const float* __restrict__ h0,
                          const float* __restrict__ c0,
                          const int* __restrict__ w1, const int* __restrict__ w2,
                          float* __restrict__ bh, float* __restrict__ bc,
                          f16* __restrict__ x0hi, f16* __restrict__ x0lo,
                          f16* __restrict__ h0hi, f16* __restrict__ h0lo,
                          float4* __restrict__ stepc,
                          int* __restrict__ flags)
{
  int e = blockIdx.x * 256 + threadIdx.x;   // grid 4096 -> 1048576
  int r = e & (BH - 1);
  bh[e] = h0[r];
  bc[e] = c0[r];
  if (e < BH) {
    float v = h0[e];
    f16 hi = (f16)v;
    h0hi[e] = hi;
    h0lo[e] = (f16)(v - (float)hi);
  }
  if (e < BB*DD) {
    int b = e >> 8, d = e & 255;
    float v = x0[(size_t)b*(TT*DD) + d];
    f16 hi = (f16)v;
    x0hi[e] = hi;
    x0lo[e] = (f16)(v - (float)hi);
  }
  if (e < TT) {
    float a1 = (float)w1[e], a2 = (float)w2[e];
    stepc[e] = make_float4(a1, a2, 1.f / (a1 + a2), 0.f);
  }
  if (e < 4096) flags[e] = 0;
}

// ---------------- persistent main kernel ----------------

// K=512 dual-N-tile 16x16x32 MFMA GEMM with A-fragments loaded DIRECTLY from
// the L3-coherent X slot (relaxed agent atomic 8B loads -> dwordx2 sc0 sc1).
// A-frag for lane: row = lane&15, k = ks*32 + (lane>>4)*8 -> contiguous 16B.
__device__ __forceinline__ void gemm16D(const f16x8 (&wA)[16], const f16x8 (&wB)[16],
                                        const unsigned* __restrict__ Xs, int lane,
                                        f32x4& acc0, f32x4& acc1) {
  const int r  = lane & 15;
  const int kc = lane >> 4;            // 0..3
  const unsigned long long* src =
      (const unsigned long long*)(Xs + (size_t)r * 256) + kc * 2;
  unsigned long long v[32];
  #pragma unroll
  for (int ks = 0; ks < 16; ++ks) {
    v[2*ks]   = __hip_atomic_load(src + ks * 8,     __ATOMIC_RELAXED,
                                  __HIP_MEMORY_SCOPE_AGENT);
    v[2*ks+1] = __hip_atomic_load(src + ks * 8 + 1, __ATOMIC_RELAXED,
                                  __HIP_MEMORY_SCOPE_AGENT);
  }
  #pragma unroll
  for (int ks = 0; ks < 16; ++ks) {
    union { unsigned long long u[2]; f16x8 f; } cvt;
    cvt.u[0] = v[2*ks];
    cvt.u[1] = v[2*ks+1];
    acc0 = __builtin_amdgcn_mfma_f32_16x16x32_f16(cvt.f, wA[ks], acc0, 0, 0, 0);
    acc1 = __builtin_amdgcn_mfma_f32_16x16x32_f16(cvt.f, wB[ks], acc1, 0, 0, 0);
  }
}

// 144 blocks x 512 threads (8 waves).
// bid 0..127: gates. grp = bid&15 owns batch rows [16g,16g+16); role = bid>>4
//             owns j-slice [64r,64r+64) x 4 gates.
// bid 128..143: out-projection block per group, lagging on a 4-slot ring.
// Flags: one 64-B line per flag — flags[(grp*9+r)*FSTRIDE] = steps done by
// block r (r=8: out block). Every wave polls independently (load-only),
// then loads A directly from X — no staging, no poll/stage barriers.
__global__ __launch_bounds__(512, 2) void lstm_persist(
    const f16* __restrict__ x0hi, const f16* __restrict__ x0lo,
    const f16* __restrict__ h0hi, const f16* __restrict__ h0lo,
    const float* __restrict__ c0,
    const f16* __restrict__ Wih16, const f16* __restrict__ Whh16,
    const f16* __restrict__ Wbig16, const f16* __restrict__ Wlin16,
    const float* __restrict__ bias0, const float* __restrict__ bias1,
    const float* __restrict__ b_lin,
    const float4* __restrict__ stepc,
    unsigned* __restrict__ X,                 // 4 slots x 16 grp x XSLOT_U32
    float* __restrict__ bh, float* __restrict__ bc,
    int* __restrict__ flags,
    float* __restrict__ outp)
{
  __shared__ float gbuf[4096];      // 16 KB: [gate][m<16][64 j], col-swizzled

  const int tid  = threadIdx.x;
  const int lane = tid & 63;
  const int wv   = tid >> 6;            // wave 0..7
  const int bid  = blockIdx.x;
  const bool isG = bid < 128;
  const int grp  = isG ? (bid & 15) : (bid - 128);
  const int role = bid >> 4;            // gates only: 0..7
  const int b0   = grp * GR;
  const int r16  = lane & 15;
  const int kc   = lane >> 4;           // 0..3
  const int ksel = kc * 8;

  int* gflag = flags + grp * 9 * FSTRIDE;   // flag r at gflag[r*FSTRIDE]

  // ---- persistent W fragments: two 16-row N-tiles x K=512 -> 128 VGPR ----
  int rowA, rowB;
  const f16* wsrc;
  if (isG) {
    rowA = (wv & 3) * 512 + role * 64 + (wv >> 2) * 32 + r16;   // W_big row
    rowB = rowA + 16;
    wsrc = Wbig16;
  } else {
    rowA = wv * 32 + r16;                                       // W_lin row (d-col)
    rowB = rowA + 16;
    wsrc = Wlin16;
  }
  f16x8 wA[16], wB[16];
  #pragma unroll
  for (int ks = 0; ks < 16; ++ks) {
    wA[ks] = *(const f16x8*)(wsrc + (size_t)rowA * HH + ks * 32 + ksel);
    wB[ks] = *(const f16x8*)(wsrc + (size_t)rowB * HH + ks * 32 + ksel);
  }

  if (isG) {
    // ---- per-thread epilogue constants (2 cells/thread) ----
    int   eidx[2];
    float creg[2];
    const int jl = tid & 63;
    const int jg = role * 64 + jl;
    const float bI = bias1[jg],        bF = bias1[512 + jg];
    const float bG = bias1[1024 + jg], bO = bias1[1536 + jg];
    #pragma unroll
    for (int i = 0; i < 2; ++i) {
      int c = i * 512 + tid;
      int bl = c >> 6;                  // 0..15
      eidx[i] = (b0 + bl) * HH + jg;
      creg[i] = c0[eidx[i]];
    }

    for (int t = 0; t < TT; ++t) {
      // skip-buffer prefetch FIRST: latency hides under the flag spin
      const float4 sc = stepc[t];
      const int pos = t & (SS - 1);
      float shv[2], scv[2];
      #pragma unroll
      for (int i = 0; i < 2; ++i) {
        int bx = pos * BH + eidx[i];
        shv[i] = bh[bx];
        scv[i] = bc[bx];
      }

      f32x4 acc0, acc1;
      #pragma unroll
      for (int i = 0; i < 4; ++i) { acc0[i] = 0.f; acc1[i] = 0.f; }
      if (t == 0) {
        const f16* arh = x0hi + (size_t)(b0 + r16) * DD;
        const f16* arl = x0lo + (size_t)(b0 + r16) * DD;
        const f16* wap = Wih16 + (size_t)rowA * DD;
        const f16* wbp = Wih16 + (size_t)rowB * DD;
        #pragma unroll
        for (int ks = 0; ks < 8; ++ks) {          // K=256: x0 @ W_ih^T
          int ko = ks * 32 + ksel;
          f16x8 wa = *(const f16x8*)(wap + ko);
          f16x8 wb = *(const f16x8*)(wbp + ko);
          f16x8 ah = *(const f16x8*)(arh + ko);
          f16x8 al = *(const f16x8*)(arl + ko);
          acc0 = __builtin_amdgcn_mfma_f32_16x16x32_f16(ah, wa, acc0, 0, 0, 0);
          acc1 = __builtin_amdgcn_mfma_f32_16x16x32_f16(ah, wb, acc1, 0, 0, 0);
          acc0 = __builtin_amdgcn_mfma_f32_16x16x32_f16(al, wa, acc0, 0, 0, 0);
          acc1 = __builtin_amdgcn_mfma_f32_16x16x32_f16(al, wb, acc1, 0, 0, 0);
        }
        const f16* brh = h0hi + (size_t)(b0 + r16) * HH;
        const f16* brl = h0lo + (size_t)(b0 + r16) * HH;
        const f16* qap = Whh16 + (size_t)rowA * HH;
        const f16* qbp = Whh16 + (size_t)rowB * HH;
        #pragma unroll
        for (int ks = 0; ks < 16; ++ks) {         // K=512: h0 @ W_hh^T
          int ko = ks * 32 + ksel;
          f16x8 wa = *(const f16x8*)(qap + ko);
          f16x8 wb = *(const f16x8*)(qbp + ko);
          f16x8 ah = *(const f16x8*)(brh + ko);
          f16x8 al = *(const f16x8*)(brl + ko);
          acc0 = __builtin_amdgcn_mfma_f32_16x16x32_f16(ah, wa, acc0, 0, 0, 0);
          acc1 = __builtin_amdgcn_mfma_f32_16x16x32_f16(ah, wb, acc1, 0, 0, 0);
          acc0 = __builtin_amdgcn_mfma_f32_16x16x32_f16(al, wa, acc0, 0, 0, 0);
          acc1 = __builtin_amdgcn_mfma_f32_16x16x32_f16(al, wb, acc1, 0, 0, 0);
        }
      } else {
        // per-wave poll (lanes 0..7 -> producer flags; lane 8 -> ring guard)
        if (lane < 8) {
          while (__hip_atomic_load(&gflag[lane * FSTRIDE], __ATOMIC_RELAXED,
                                   __HIP_MEMORY_SCOPE_AGENT) < t) {}
        } else if (lane == 8 && t >= 4) {
          while (__hip_atomic_load(&gflag[8 * FSTRIDE], __ATOMIC_RELAXED,
                                   __HIP_MEMORY_SCOPE_AGENT) < t - 3) {}
        }
        gemm16D(wA, wB,
                X + (size_t)(((t - 1) & 3) * NGRP + grp) * XSLOT_U32,
                lane, acc0, acc1);
      }

      // acc -> gbuf [gate][m][64 j], column swizzled by +16*(m>>2)
      {
        const int g4 = wv & 3, jh = wv >> 2;
        #pragma unroll
        for (int rg = 0; rg < 4; ++rg) {
          int m  = kc * 4 + rg;
          int j0 = jh * 32 + r16;
          int cs0 = (j0      + 16 * kc) & 63;
          int cs1 = (j0 + 16 + 16 * kc) & 63;
          gbuf[g4 * 1024 + m * 64 + cs0] = acc0[rg];
          gbuf[g4 * 1024 + m * 64 + cs1] = acc1[rg];
        }
      }
      __syncthreads();                  // gbuf ready (also fences ring guard for writers)

      // epilogue phase 1: gate math up to ch, publish X, flag
      const float a1 = sc.x, a2 = sc.y, nrm = sc.z;
      float baI = bI, baF = bF, baG = bG, baO = bO;
      if (t == 0) {
        baI = bias0[jg];        baF = bias0[512 + jg];
        baG = bias0[1024 + jg]; baO = bias0[1536 + jg];
      }
      unsigned* Xw = X + (size_t)((t & 3) * NGRP + grp) * XSLOT_U32;
      float hnv[2], cnv[2], chv[2];
      #pragma unroll
      for (int i = 0; i < 2; ++i) {
        int c = i * 512 + tid;
        int bl = c >> 6;                           // m
        int jj = c & 63;
        int gofs = bl * 64 + ((jj + 16 * (bl >> 2)) & 63);
        float pi = gbuf[gofs]        + baI;
        float pf = gbuf[1024 + gofs] + baF;
        float pg = gbuf[2048 + gofs] + baG;
        float po = gbuf[3072 + gofs] + baO;
        float i_ = sigm(pi), f_ = sigm(pf), o_ = sigm(po), g_ = ftanh(pg);
        float cnew = fmaf(f_, creg[i], i_ * g_);
        float hnew = o_ * ftanh(cnew);
        float ch = (a1 * hnew + a2 * ftanh(shv[i])) * nrm;
        hnv[i] = hnew; cnv[i] = cnew; chv[i] = ch;
        f16 hv = (f16)ch;
        unsigned hb = (unsigned)*(const unsigned short*)&hv;
        unsigned part = (unsigned)__shfl_xor((int)hb, 1);
        if ((tid & 1) == 0)
          __hip_atomic_store(&Xw[bl * 256 + (jg >> 1)], hb | (part << 16),
                             __ATOMIC_RELAXED, __HIP_MEMORY_SCOPE_AGENT);
      }
      __syncthreads();                 // drains X stores of all waves (vmcnt 0)
      if (tid == 0)
        __hip_atomic_store(&gflag[role * FSTRIDE], t + 1, __ATOMIC_RELAXED,
                           __HIP_MEMORY_SCOPE_AGENT);

      // epilogue phase 2 (off critical path): cc, skip buffers, finals
      #pragma unroll
      for (int i = 0; i < 2; ++i) {
        float cc = (a1 * cnv[i] + a2 * ftanh(scv[i])) * nrm;
        creg[i] = cc;
        int bx = pos * BH + eidx[i];
        bh[bx] = hnv[i];
        bc[bx] = cnv[i];
        if (t == TT - 1) {
          __builtin_nontemporal_store(chv[i], &outp[OUT_BASE + eidx[i]]);       // h_fin
          __builtin_nontemporal_store(cc,     &outp[OUT_BASE + BH + eidx[i]]);  // c_fin
        }
      }
    }
  } else {
    // ---------- lagging out-projection block (one per group) ----------
    const float bld0 = b_lin[rowA];
    const float bld1 = b_lin[rowB];
    for (int s = 0; s < TT; ++s) {
      if (lane < 8) {
        while (__hip_atomic_load(&gflag[lane * FSTRIDE], __ATOMIC_RELAXED,
                                 __HIP_MEMORY_SCOPE_AGENT) < s + 1) {}
      }
      f32x4 acc0, acc1;
      #pragma unroll
      for (int i = 0; i < 4; ++i) { acc0[i] = 0.f; acc1[i] = 0.f; }
      gemm16D(wA, wB,
              X + (size_t)((s & 3) * NGRP + grp) * XSLOT_U32,
              lane, acc0, acc1);
      __syncthreads();                 // all waves consumed slot s
      if (tid == 0)                    // release slot for producers
        __hip_atomic_store(&gflag[8 * FSTRIDE], s + 1, __ATOMIC_RELAXED,
                           __HIP_MEMORY_SCOPE_AGENT);
      const size_t tbase = (size_t)s * DD + wv * 32 + r16;
      #pragma unroll
      for (int rg = 0; rg < 4; ++rg) {
        int m = kc * 4 + rg;
        __builtin_nontemporal_store(acc0[rg] + bld0,
                                    &outp[(size_t)(b0 + m) * (TT*DD) + tbase]);
        __builtin_nontemporal_store(acc1[rg] + bld1,
                                    &outp[(size_t)(b0 + m) * (TT*DD) + tbase + 16]);
      }
    }
  }
}

// ---------------- host launch ----------------

extern "C" void kernel_launch(void* const* d_in, const int* in_sizes, int n_in,
                              void* d_out, int out_size, void* d_ws, size_t ws_size,
                              hipStream_t stream)
{
  const float* x0    = (const float*)d_in[0];
  const float* h0    = (const float*)d_in[1];
  const float* c0    = (const float*)d_in[2];
  const float* W_ih  = (const float*)d_in[3];
  const float* W_hh  = (const float*)d_in[4];
  const float* b_ih  = (const float*)d_in[5];
  const float* b_hh  = (const float*)d_in[6];
  const float* W_lin = (const float*)d_in[7];
  const float* b_lin = (const float*)d_in[8];
  const int*   w1    = (const int*)d_in[9];
  const int*   w2    = (const int*)d_in[10];

  char* p = (char*)d_ws;
  f16* Wbig16 = (f16*)p;            p += (size_t)G4H*HH*2;
  f16* Wih16  = (f16*)p;            p += (size_t)G4H*DD*2;
  f16* Whh16  = (f16*)p;            p += (size_t)G4H*HH*2;
  f16* Wlin16 = (f16*)p;            p += (size_t)DD*HH*2;
  f16* x0hi   = (f16*)p;            p += (size_t)BB*DD*2;
  f16* x0lo   = (f16*)p;            p += (size_t)BB*DD*2;
  f16* h0hi   = (f16*)p;            p += (size_t)BH*2;
  f16* h0lo   = (f16*)p;            p += (size_t)BH*2;
  unsigned* X = (unsigned*)p;       p += (size_t)4*NGRP*XSLOT_U32*4;   // 1 MB
  float* bh   = (float*)p;          p += (size_t)SS*BH*4;
  float* bc   = (float*)p;          p += (size_t)SS*BH*4;
  float* bias0= (float*)p;          p += G4H*4;
  float* bias1= (float*)p;          p += G4H*4;
  float4* stepc = (float4*)p;       p += (size_t)TT*16;
  int*  flags = (int*)p;            p += 4096*4;
  float* outp = (float*)d_out;

  hipLaunchKernelGGL(prep_wbig16, dim3(32, 8), dim3(256), 0, stream,
                     W_ih, W_hh, W_lin, Wbig16);
  hipLaunchKernelGGL(prep_bias, dim3(8), dim3(256), 0, stream,
                     b_ih, b_hh, W_ih, b_lin, bias0, bias1);
  hipLaunchKernelGGL(prep_cvtw, dim3(6656), dim3(256), 0, stream,
                     W_ih, W_hh, W_lin, Wih16, Whh16, Wlin16);
  hipLaunchKernelGGL(prep_init, dim3(4096), dim3(256), 0, stream,
                     x0, h0, c0, w1, w2, bh, bc, x0hi, x0lo, h0hi, h0lo, stepc, flags);

  hipLaunchKernelGGL(lstm_persist, dim3(128 + NGRP), dim3(512), 0, stream,
                     x0hi, x0lo, h0hi, h0lo, c0, Wih16, Whh16, Wbig16, Wlin16,
                     bias0, bias1, b_lin, stepc, X, bh, bc, flags, outp);
}

// Round 18
// 1600.893 us; speedup vs baseline: 2.9199x; 2.9199x over previous
//
#include <hip/hip_runtime.h>
#include <math.h>

#define BB 256
#define TT 512
#define DD 256
#define HH 512
#define SS 8
#define G4H 2048
#define BH (BB*HH)          // 131072
#define OUT_BASE ((size_t)BB*TT*DD)
#define NGRP 16
#define GR 16               // batch rows per group
#define XSLOT_U32 4096      // 16 KB per group-slot: 16 rows x 256 u32 (fp16 pairs)
#define FSTRIDE 16          // ints between flags (64 B): one cache line per flag

typedef _Float16 f16;
typedef __attribute__((ext_vector_type(8))) _Float16 f16x8;
typedef __attribute__((ext_vector_type(4))) float    f32x4;

__device__ __forceinline__ float sigm(float x) { return 1.f / (1.f + __expf(-x)); }
__device__ __forceinline__ float ftanh(float x) {
  x = fminf(15.f, fmaxf(-15.f, x));
  float e = __expf(-2.f * x);
  return (1.f - e) / (1.f + e);
}

// ---------------- prep kernels ----------------

__global__ __launch_bounds__(256) void prep_wbig16(
    const float* __restrict__ W_ih, const float* __restrict__ W_hh,
    const float* __restrict__ W_lin, f16* __restrict__ Wbig16)
{
  __shared__ float As[64][20];
  __shared__ float Bs[16][68];
  const int n0 = blockIdx.x * 64;
  const int j0 = blockIdx.y * 64;
  const int tid = threadIdx.x;
  const int tn = tid >> 4, tj = tid & 15;
  float acc[4][4] = {};
  for (int k0 = 0; k0 < DD; k0 += 16) {
    { int r = tid >> 2, c = (tid & 3) * 4;
      *(float4*)&As[r][c] = *(const float4*)&W_ih[(size_t)(n0 + r) * DD + k0 + c]; }
    { int r = tid >> 4, c = (tid & 15) * 4;
      *(float4*)&Bs[r][c] = *(const float4*)&W_lin[(size_t)(k0 + r) * HH + j0 + c]; }
    __syncthreads();
    #pragma unroll
    for (int k = 0; k < 16; ++k) {
      float a[4], bv[4];
      #pragma unroll
      for (int i = 0; i < 4; ++i) a[i] = As[tn*4+i][k];
      #pragma unroll
      for (int m = 0; m < 4; ++m) bv[m] = Bs[k][tj*4+m];
      #pragma unroll
      for (int i = 0; i < 4; ++i)
        #pragma unroll
        for (int m = 0; m < 4; ++m)
          acc[i][m] = fmaf(a[i], bv[m], acc[i][m]);
    }
    __syncthreads();
  }
  #pragma unroll
  for (int i = 0; i < 4; ++i) {
    int n = n0 + tn*4 + i;
    #pragma unroll
    for (int m = 0; m < 4; ++m) {
      int j = j0 + tj*4 + m;
      Wbig16[(size_t)n*HH + j] = (f16)(acc[i][m] + W_hh[(size_t)n*HH + j]);
    }
  }
}

__global__ void prep_bias(const float* __restrict__ b_ih, const float* __restrict__ b_hh,
                          const float* __restrict__ W_ih, const float* __restrict__ b_lin,
                          float* __restrict__ bias0, float* __restrict__ bias1)
{
  int n = blockIdx.x * 256 + threadIdx.x;   // grid 8
  float s = b_ih[n] + b_hh[n];
  float d = 0.f;
  for (int k = 0; k < DD; ++k) d = fmaf(W_ih[(size_t)n*DD + k], b_lin[k], d);
  bias0[n] = s;
  bias1[n] = s + d;
}

#define NIH (G4H*DD)
#define NHH (G4H*HH)
__global__ void prep_cvtw(const float* __restrict__ W_ih, const float* __restrict__ W_hh,
                          const float* __restrict__ W_lin,
                          f16* __restrict__ Wih16, f16* __restrict__ Whh16,
                          f16* __restrict__ Wlin16)
{
  int e = blockIdx.x * 256 + threadIdx.x;   // grid 6656
  if (e < NIH) Wih16[e] = (f16)W_ih[e];
  else if (e < NIH + NHH) Whh16[e - NIH] = (f16)W_hh[e - NIH];
  else Wlin16[e - NIH - NHH] = (f16)W_lin[e - NIH - NHH];
}

__global__ void prep_init(const float* __restrict__ x0, const float* __restrict__ h0,
                          const float* __restrict__ c0,
                          const int* __restrict__ w1, const int* __restrict__ w2,
                          float* __restrict__ bh, float* __restrict__ bc,
                          f16* __restrict__ x0hi, f16* __restrict__ x0lo,
                          f16* __restrict__ h0hi, f16* __restrict__ h0lo,
                          float4* __restrict__ stepc,
                          int* __restrict__ flags)
{
  int e = blockIdx.x * 256 + threadIdx.x;   // grid 4096 -> 1048576
  int r = e & (BH - 1);
  bh[e] = h0[r];
  bc[e] = c0[r];
  if (e < BH) {
    float v = h0[e];
    f16 hi = (f16)v;
    h0hi[e] = hi;
    h0lo[e] = (f16)(v - (float)hi);
  }
  if (e < BB*DD) {
    int b = e >> 8, d = e & 255;
    float v = x0[(size_t)b*(TT*DD) + d];
    f16 hi = (f16)v;
    x0hi[e] = hi;
    x0lo[e] = (f16)(v - (float)hi);
  }
  if (e < TT) {
    float a1 = (float)w1[e], a2 = (float)w2[e];
    stepc[e] = make_float4(a1, a2, 1.f / (a1 + a2), 0.f);
  }
  if (e < 4096) flags[e] = 0;
}

// ---------------- persistent main kernel ----------------

// Stage one 16 KB group-slot (fp16 plane, 16 rows x 512 cols) into linear LDS
// via global_load_lds (16B/lane, sc0|sc1 for L3 coherence). 8 waves x 2 rows.
// XOR swizzle on the per-lane GLOBAL source address: LDS unit u holds src unit u^r.
__device__ __forceinline__ void stageG(const unsigned* __restrict__ Xs,
                                       f16* lds, int tid) {
  const int lane = tid & 63;
  const int wv = tid >> 6;
  #pragma unroll
  for (int i = 0; i < 2; ++i) {
    int r = wv * 2 + i;                 // row 0..15 (wave-uniform)
    const char* src = (const char*)Xs + (size_t)r * 1024 +
                      (size_t)((lane ^ r) & 63) * 16;
    __builtin_amdgcn_global_load_lds(
        (const __attribute__((address_space(1))) void*)src,
        (__attribute__((address_space(3))) void*)((char*)lds + r * 1024),
        16, 0, 0x11 /* sc0|sc1 */);
  }
}

// K=512 dual-N-tile 16x16x32 MFMA GEMM from swizzled LDS, W frags in registers.
__device__ __forceinline__ void gemm16(const f16x8 (&wA)[16], const f16x8 (&wB)[16],
                                       const f16* lds, int lane,
                                       f32x4& acc0, f32x4& acc1) {
  const int r  = lane & 15;
  const int kc = lane >> 4;            // 0..3
  const int rb = r * 1024;
  #pragma unroll
  for (int ks = 0; ks < 16; ++ks) {
    int u = ks * 4 + kc;
    f16x8 a = *(const f16x8*)((const char*)lds + rb + ((u ^ r) << 4));
    acc0 = __builtin_amdgcn_mfma_f32_16x16x32_f16(a, wA[ks], acc0, 0, 0, 0);
    acc1 = __builtin_amdgcn_mfma_f32_16x16x32_f16(a, wB[ks], acc1, 0, 0, 0);
  }
}

// 144 blocks x 512 threads (8 waves).
// bid 0..127: gates. grp = bid&15 owns batch rows [16g,16g+16); role = bid>>4
//             owns j-slice [64r,64r+64) x 4 gates.
// bid 128..143: out-projection block per group, lagging on a 4-slot ring.
// Flags: one 64-B line per flag — flags[(grp*9+r)*FSTRIDE] = steps done by
// block r (r=8: out block, posted right after its stage completes).
// PER-WAVE POLL: every wave polls the flag lines itself (lanes 0..8,
// load-only) and issues its staging rows immediately on detection — removes
// the wave0-detect -> barrier -> stage handoff (3 barriers/step, was 4).
__global__ __launch_bounds__(512, 2) void lstm_persist(
    const f16* __restrict__ x0hi, const f16* __restrict__ x0lo,
    const f16* __restrict__ h0hi, const f16* __restrict__ h0lo,
    const float* __restrict__ c0,
    const f16* __restrict__ Wih16, const f16* __restrict__ Whh16,
    const f16* __restrict__ Wbig16, const f16* __restrict__ Wlin16,
    const float* __restrict__ bias0, const float* __restrict__ bias1,
    const float* __restrict__ b_lin,
    const float4* __restrict__ stepc,
    unsigned* __restrict__ X,                 // 4 slots x 16 grp x XSLOT_U32
    float* __restrict__ bh, float* __restrict__ bc,
    int* __restrict__ flags,
    float* __restrict__ outp)
{
  __shared__ f16 LdsA[8192];        // 16 KB: 16 rows x 512 cols (exact fit)
  __shared__ float gbuf[4096];      // 16 KB: [gate][m<16][64 j], col-swizzled

  const int tid  = threadIdx.x;
  const int lane = tid & 63;
  const int wv   = tid >> 6;            // wave 0..7
  const int bid  = blockIdx.x;
  const bool isG = bid < 128;
  const int grp  = isG ? (bid & 15) : (bid - 128);
  const int role = bid >> 4;            // gates only: 0..7
  const int b0   = grp * GR;
  const int r16  = lane & 15;
  const int kc   = lane >> 4;           // 0..3
  const int ksel = kc * 8;

  int* gflag = flags + grp * 9 * FSTRIDE;   // flag r at gflag[r*FSTRIDE]

  // ---- persistent W fragments: two 16-row N-tiles x K=512 -> 128 VGPR ----
  int rowA, rowB;
  const f16* wsrc;
  if (isG) {
    rowA = (wv & 3) * 512 + role * 64 + (wv >> 2) * 32 + r16;   // W_big row
    rowB = rowA + 16;
    wsrc = Wbig16;
  } else {
    rowA = wv * 32 + r16;                                       // W_lin row (d-col)
    rowB = rowA + 16;
    wsrc = Wlin16;
  }
  f16x8 wA[16], wB[16];
  #pragma unroll
  for (int ks = 0; ks < 16; ++ks) {
    wA[ks] = *(const f16x8*)(wsrc + (size_t)rowA * HH + ks * 32 + ksel);
    wB[ks] = *(const f16x8*)(wsrc + (size_t)rowB * HH + ks * 32 + ksel);
  }

  if (isG) {
    // ---- per-thread epilogue constants (2 cells/thread) ----
    int   eidx[2];
    float creg[2];
    const int jl = tid & 63;
    const int jg = role * 64 + jl;
    const float bI = bias1[jg],        bF = bias1[512 + jg];
    const float bG = bias1[1024 + jg], bO = bias1[1536 + jg];
    #pragma unroll
    for (int i = 0; i < 2; ++i) {
      int c = i * 512 + tid;
      int bl = c >> 6;                  // 0..15
      eidx[i] = (b0 + bl) * HH + jg;
      creg[i] = c0[eidx[i]];
    }

    for (int t = 0; t < TT; ++t) {
      if (t > 0) {
        // per-wave poll (load-only, one 64-B line per flag), then stage own rows
        if (lane < 8) {
          while (__hip_atomic_load(&gflag[lane * FSTRIDE], __ATOMIC_RELAXED,
                                   __HIP_MEMORY_SCOPE_AGENT) < t) {}
        } else if (lane == 8 && t >= 4) {
          while (__hip_atomic_load(&gflag[8 * FSTRIDE], __ATOMIC_RELAXED,
                                   __HIP_MEMORY_SCOPE_AGENT) < t - 3) {}
        }
        stageG(X + (size_t)(((t - 1) & 3) * NGRP + grp) * XSLOT_U32, LdsA, tid);
      }

      // prefetch step constants + skip reads (overlap with staging flight)
      const float4 sc = stepc[t];
      const int pos = t & (SS - 1);
      float shv[2], scv[2];
      #pragma unroll
      for (int i = 0; i < 2; ++i) {
        int bx = pos * BH + eidx[i];
        shv[i] = bh[bx];
        scv[i] = bc[bx];
      }

      f32x4 acc0, acc1;
      #pragma unroll
      for (int i = 0; i < 4; ++i) { acc0[i] = 0.f; acc1[i] = 0.f; }
      if (t == 0) {
        const f16* arh = x0hi + (size_t)(b0 + r16) * DD;
        const f16* arl = x0lo + (size_t)(b0 + r16) * DD;
        const f16* wap = Wih16 + (size_t)rowA * DD;
        const f16* wbp = Wih16 + (size_t)rowB * DD;
        #pragma unroll
        for (int ks = 0; ks < 8; ++ks) {          // K=256: x0 @ W_ih^T
          int ko = ks * 32 + ksel;
          f16x8 wa = *(const f16x8*)(wap + ko);
          f16x8 wb = *(const f16x8*)(wbp + ko);
          f16x8 ah = *(const f16x8*)(arh + ko);
          f16x8 al = *(const f16x8*)(arl + ko);
          acc0 = __builtin_amdgcn_mfma_f32_16x16x32_f16(ah, wa, acc0, 0, 0, 0);
          acc1 = __builtin_amdgcn_mfma_f32_16x16x32_f16(ah, wb, acc1, 0, 0, 0);
          acc0 = __builtin_amdgcn_mfma_f32_16x16x32_f16(al, wa, acc0, 0, 0, 0);
          acc1 = __builtin_amdgcn_mfma_f32_16x16x32_f16(al, wb, acc1, 0, 0, 0);
        }
        const f16* brh = h0hi + (size_t)(b0 + r16) * HH;
        const f16* brl = h0lo + (size_t)(b0 + r16) * HH;
        const f16* qap = Whh16 + (size_t)rowA * HH;
        const f16* qbp = Whh16 + (size_t)rowB * HH;
        #pragma unroll
        for (int ks = 0; ks < 16; ++ks) {         // K=512: h0 @ W_hh^T
          int ko = ks * 32 + ksel;
          f16x8 wa = *(const f16x8*)(qap + ko);
          f16x8 wb = *(const f16x8*)(qbp + ko);
          f16x8 ah = *(const f16x8*)(brh + ko);
          f16x8 al = *(const f16x8*)(brl + ko);
          acc0 = __builtin_amdgcn_mfma_f32_16x16x32_f16(ah, wa, acc0, 0, 0, 0);
          acc1 = __builtin_amdgcn_mfma_f32_16x16x32_f16(ah, wb, acc1, 0, 0, 0);
          acc0 = __builtin_amdgcn_mfma_f32_16x16x32_f16(al, wa, acc0, 0, 0, 0);
          acc1 = __builtin_amdgcn_mfma_f32_16x16x32_f16(al, wb, acc1, 0, 0, 0);
        }
      } else {
        __syncthreads();                 // staging complete (vmcnt drained here)
        gemm16(wA, wB, LdsA, lane, acc0, acc1);
      }

      // acc -> gbuf [gate][m][64 j], column swizzled by +16*(m>>2)
      {
        const int g4 = wv & 3, jh = wv >> 2;
        #pragma unroll
        for (int rg = 0; rg < 4; ++rg) {
          int m  = kc * 4 + rg;
          int j0 = jh * 32 + r16;
          int cs0 = (j0      + 16 * kc) & 63;
          int cs1 = (j0 + 16 + 16 * kc) & 63;
          gbuf[g4 * 1024 + m * 64 + cs0] = acc0[rg];
          gbuf[g4 * 1024 + m * 64 + cs1] = acc1[rg];
        }
      }
      __syncthreads();

      // epilogue phase 1: gate math up to ch, publish X, flag
      const float a1 = sc.x, a2 = sc.y, nrm = sc.z;
      float baI = bI, baF = bF, baG = bG, baO = bO;
      if (t == 0) {
        baI = bias0[jg];        baF = bias0[512 + jg];
        baG = bias0[1024 + jg]; baO = bias0[1536 + jg];
      }
      unsigned* Xw = X + (size_t)((t & 3) * NGRP + grp) * XSLOT_U32;
      float hnv[2], cnv[2], chv[2];
      #pragma unroll
      for (int i = 0; i < 2; ++i) {
        int c = i * 512 + tid;
        int bl = c >> 6;                           // m
        int jj = c & 63;
        int gofs = bl * 64 + ((jj + 16 * (bl >> 2)) & 63);
        float pi = gbuf[gofs]        + baI;
        float pf = gbuf[1024 + gofs] + baF;
        float pg = gbuf[2048 + gofs] + baG;
        float po = gbuf[3072 + gofs] + baO;
        float i_ = sigm(pi), f_ = sigm(pf), o_ = sigm(po), g_ = ftanh(pg);
        float cnew = fmaf(f_, creg[i], i_ * g_);
        float hnew = o_ * ftanh(cnew);
        float ch = (a1 * hnew + a2 * ftanh(shv[i])) * nrm;
        hnv[i] = hnew; cnv[i] = cnew; chv[i] = ch;
        f16 hv = (f16)ch;
        unsigned hb = (unsigned)*(const unsigned short*)&hv;
        unsigned part = (unsigned)__shfl_xor((int)hb, 1);
        if ((tid & 1) == 0)
          __hip_atomic_store(&Xw[bl * 256 + (jg >> 1)], hb | (part << 16),
                             __ATOMIC_RELAXED, __HIP_MEMORY_SCOPE_AGENT);
      }
      __syncthreads();                 // drains X stores of all waves (vmcnt 0)
      if (tid == 0)
        __hip_atomic_store(&gflag[role * FSTRIDE], t + 1, __ATOMIC_RELAXED,
                           __HIP_MEMORY_SCOPE_AGENT);

      // epilogue phase 2 (off critical path): cc, skip buffers, finals
      #pragma unroll
      for (int i = 0; i < 2; ++i) {
        float cc = (a1 * cnv[i] + a2 * ftanh(scv[i])) * nrm;
        creg[i] = cc;
        int bx = pos * BH + eidx[i];
        bh[bx] = hnv[i];
        bc[bx] = cnv[i];
        if (t == TT - 1) {
          __builtin_nontemporal_store(chv[i], &outp[OUT_BASE + eidx[i]]);       // h_fin
          __builtin_nontemporal_store(cc,     &outp[OUT_BASE + BH + eidx[i]]);  // c_fin
        }
      }
    }
  } else {
    // ---------- lagging out-projection block (one per group) ----------
    const float bld0 = b_lin[rowA];
    const float bld1 = b_lin[rowB];
    for (int s = 0; s < TT; ++s) {
      // per-wave poll (load-only), then stage own rows immediately
      if (lane < 8) {
        while (__hip_atomic_load(&gflag[lane * FSTRIDE], __ATOMIC_RELAXED,
                                 __HIP_MEMORY_SCOPE_AGENT) < s + 1) {}
      }
      stageG(X + (size_t)((s & 3) * NGRP + grp) * XSLOT_U32, LdsA, tid);
      __syncthreads();                 // staging complete (vmcnt drained)
      if (tid == 0)                    // EARLY slot release: staged == consumed
        __hip_atomic_store(&gflag[8 * FSTRIDE], s + 1, __ATOMIC_RELAXED,
                           __HIP_MEMORY_SCOPE_AGENT);
      f32x4 acc0, acc1;
      #pragma unroll
      for (int i = 0; i < 4; ++i) { acc0[i] = 0.f; acc1[i] = 0.f; }
      gemm16(wA, wB, LdsA, lane, acc0, acc1);
      const size_t tbase = (size_t)s * DD + wv * 32 + r16;
      #pragma unroll
      for (int rg = 0; rg < 4; ++rg) {
        int m = kc * 4 + rg;
        __builtin_nontemporal_store(acc0[rg] + bld0,
                                    &outp[(size_t)(b0 + m) * (TT*DD) + tbase]);
        __builtin_nontemporal_store(acc1[rg] + bld1,
                                    &outp[(size_t)(b0 + m) * (TT*DD) + tbase + 16]);
      }
      __syncthreads();                 // all waves done reading LdsA before next stage
    }
  }
}

// ---------------- host launch ----------------

extern "C" void kernel_launch(void* const* d_in, const int* in_sizes, int n_in,
                              void* d_out, int out_size, void* d_ws, size_t ws_size,
                              hipStream_t stream)
{
  const float* x0    = (const float*)d_in[0];
  const float* h0    = (const float*)d_in[1];
  const float* c0    = (const float*)d_in[2];
  const float* W_ih  = (const float*)d_in[3];
  const float* W_hh  = (const float*)d_in[4];
  const float* b_ih  = (const float*)d_in[5];
  const float* b_hh  = (const float*)d_in[6];
  const float* W_lin = (const float*)d_in[7];
  const float* b_lin = (const float*)d_in[8];
  const int*   w1    = (const int*)d_in[9];
  const int*   w2    = (const int*)d_in[10];

  char* p = (char*)d_ws;
  f16* Wbig16 = (f16*)p;            p += (size_t)G4H*HH*2;
  f16* Wih16  = (f16*)p;            p += (size_t)G4H*DD*2;
  f16* Whh16  = (f16*)p;            p += (size_t)G4H*HH*2;
  f16* Wlin16 = (f16*)p;            p += (size_t)DD*HH*2;
  f16* x0hi   = (f16*)p;            p += (size_t)BB*DD*2;
  f16* x0lo   = (f16*)p;            p += (size_t)BB*DD*2;
  f16* h0hi   = (f16*)p;            p += (size_t)BH*2;
  f16* h0lo   = (f16*)p;            p += (size_t)BH*2;
  unsigned* X = (unsigned*)p;       p += (size_t)4*NGRP*XSLOT_U32*4;   // 1 MB
  float* bh   = (float*)p;          p += (size_t)SS*BH*4;
  float* bc   = (float*)p;          p += (size_t)SS*BH*4;
  float* bias0= (float*)p;          p += G4H*4;
  float* bias1= (float*)p;          p += G4H*4;
  float4* stepc = (float4*)p;       p += (size_t)TT*16;
  int*  flags = (int*)p;            p += 4096*4;
  float* outp = (float*)d_out;

  hipLaunchKernelGGL(prep_wbig16, dim3(32, 8), dim3(256), 0, stream,
                     W_ih, W_hh, W_lin, Wbig16);
  hipLaunchKernelGGL(prep_bias, dim3(8), dim3(256), 0, stream,
                     b_ih, b_hh, W_ih, b_lin, bias0, bias1);
  hipLaunchKernelGGL(prep_cvtw, dim3(6656), dim3(256), 0, stream,
                     W_ih, W_hh, W_lin, Wih16, Whh16, Wlin16);
  hipLaunchKernelGGL(prep_init, dim3(4096), dim3(256), 0, stream,
                     x0, h0, c0, w1, w2, bh, bc, x0hi, x0lo, h0hi, h0lo, stepc, flags);

  hipLaunchKernelGGL(lstm_persist, dim3(128 + NGRP), dim3(512), 0, stream,
                     x0hi, x0lo, h0hi, h0lo, c0, Wih16, Whh16, Wbig16, Wlin16,
                     bias0, bias1, b_lin, stepc, X, bh, bc, flags, outp);
}

// Round 19
// 1425.237 us; speedup vs baseline: 3.2798x; 1.1232x over previous
//
#include <hip/hip_runtime.h>
#include <math.h>

#define BB 256
#define TT 512
#define DD 256
#define HH 512
#define SS 8
#define G4H 2048
#define BH (BB*HH)          // 131072
#define OUT_BASE ((size_t)BB*TT*DD)
#define NGRP 16
#define GR 16               // batch rows per group
#define XSLOT_U32 4096      // 16 KB per group-slot: [role 0..7][16 rows][32 u32]
#define FSTRIDE 16          // ints between flags (64 B): one cache line per flag

typedef _Float16 f16;
typedef __attribute__((ext_vector_type(8))) _Float16 f16x8;
typedef __attribute__((ext_vector_type(4))) float    f32x4;

__device__ __forceinline__ float sigm(float x) { return 1.f / (1.f + __expf(-x)); }
__device__ __forceinline__ float ftanh(float x) {
  x = fminf(15.f, fmaxf(-15.f, x));
  float e = __expf(-2.f * x);
  return (1.f - e) / (1.f + e);
}

// ---------------- prep kernels ----------------

__global__ __launch_bounds__(256) void prep_wbig16(
    const float* __restrict__ W_ih, const float* __restrict__ W_hh,
    const float* __restrict__ W_lin, f16* __restrict__ Wbig16)
{
  __shared__ float As[64][20];
  __shared__ float Bs[16][68];
  const int n0 = blockIdx.x * 64;
  const int j0 = blockIdx.y * 64;
  const int tid = threadIdx.x;
  const int tn = tid >> 4, tj = tid & 15;
  float acc[4][4] = {};
  for (int k0 = 0; k0 < DD; k0 += 16) {
    { int r = tid >> 2, c = (tid & 3) * 4;
      *(float4*)&As[r][c] = *(const float4*)&W_ih[(size_t)(n0 + r) * DD + k0 + c]; }
    { int r = tid >> 4, c = (tid & 15) * 4;
      *(float4*)&Bs[r][c] = *(const float4*)&W_lin[(size_t)(k0 + r) * HH + j0 + c]; }
    __syncthreads();
    #pragma unroll
    for (int k = 0; k < 16; ++k) {
      float a[4], bv[4];
      #pragma unroll
      for (int i = 0; i < 4; ++i) a[i] = As[tn*4+i][k];
      #pragma unroll
      for (int m = 0; m < 4; ++m) bv[m] = Bs[k][tj*4+m];
      #pragma unroll
      for (int i = 0; i < 4; ++i)
        #pragma unroll
        for (int m = 0; m < 4; ++m)
          acc[i][m] = fmaf(a[i], bv[m], acc[i][m]);
    }
    __syncthreads();
  }
  #pragma unroll
  for (int i = 0; i < 4; ++i) {
    int n = n0 + tn*4 + i;
    #pragma unroll
    for (int m = 0; m < 4; ++m) {
      int j = j0 + tj*4 + m;
      Wbig16[(size_t)n*HH + j] = (f16)(acc[i][m] + W_hh[(size_t)n*HH + j]);
    }
  }
}

__global__ void prep_bias(const float* __restrict__ b_ih, const float* __restrict__ b_hh,
                          const float* __restrict__ W_ih, const float* __restrict__ b_lin,
                          float* __restrict__ bias0, float* __restrict__ bias1)
{
  int n = blockIdx.x * 256 + threadIdx.x;   // grid 8
  float s = b_ih[n] + b_hh[n];
  float d = 0.f;
  for (int k = 0; k < DD; ++k) d = fmaf(W_ih[(size_t)n*DD + k], b_lin[k], d);
  bias0[n] = s;
  bias1[n] = s + d;
}

#define NIH (G4H*DD)
#define NHH (G4H*HH)
__global__ void prep_cvtw(const float* __restrict__ W_ih, const float* __restrict__ W_hh,
                          const float* __restrict__ W_lin,
                          f16* __restrict__ Wih16, f16* __restrict__ Whh16,
                          f16* __restrict__ Wlin16)
{
  int e = blockIdx.x * 256 + threadIdx.x;   // grid 6656
  if (e < NIH) Wih16[e] = (f16)W_ih[e];
  else if (e < NIH + NHH) Whh16[e - NIH] = (f16)W_hh[e - NIH];
  else Wlin16[e - NIH - NHH] = (f16)W_lin[e - NIH - NHH];
}

__global__ void prep_init(const float* __restrict__ x0, const float* __restrict__ h0,
                          const float* __restrict__ c0,
                          const int* __restrict__ w1, const int* __restrict__ w2,
                          float* __restrict__ bh, float* __restrict__ bc,
                          f16* __restrict__ x0hi, f16* __restrict__ x0lo,
                          f16* __restrict__ h0hi, f16* __restrict__ h0lo,
                          float4* __restrict__ stepc,
                          int* __restrict__ flags)
{
  int e = blockIdx.x * 256 + threadIdx.x;   // grid 4096 -> 1048576
  int r = e & (BH - 1);
  bh[e] = h0[r];
  bc[e] = c0[r];
  if (e < BH) {
    float v = h0[e];
    f16 hi = (f16)v;
    h0hi[e] = hi;
    h0lo[e] = (f16)(v - (float)hi);
  }
  if (e < BB*DD) {
    int b = e >> 8, d = e & 255;
    float v = x0[(size_t)b*(TT*DD) + d];
    f16 hi = (f16)v;
    x0hi[e] = hi;
    x0lo[e] = (f16)(v - (float)hi);
  }
  if (e < TT) {
    float a1 = (float)w1[e], a2 = (float)w2[e];
    stepc[e] = make_float4(a1, a2, 1.f / (a1 + a2), 0.f);
  }
  if (e < 4096) flags[e] = 0;
}

// ---------------- persistent main kernel ----------------

// Stage role-w stripe (2 KB: 16 rows x 32 u32) of one slot into LDS via
// global_load_lds. Source carries the bank swizzle: LDS unit q (row=q>>3,
// phys-u=q&7) is filled from logical unit (q&7)^(row&7). LDS dest linear.
// Executed by wave w only after its flag-w poll.
__device__ __forceinline__ void stage_stripe(const unsigned* __restrict__ Xs,
                                             int w, f16* lds, int lane) {
  #pragma unroll
  for (int i = 0; i < 2; ++i) {
    int q = i * 64 + lane;              // unit 0..127 (16 B each)
    int row = q >> 3, u = q & 7;
    const char* src = (const char*)Xs + w * 2048 + row * 128 +
                      ((u ^ (row & 7)) << 4);
    __builtin_amdgcn_global_load_lds(
        (const __attribute__((address_space(1))) void*)src,
        (__attribute__((address_space(3))) void*)((char*)lds + w * 2048 + i * 1024),
        16, 0, 0x11 /* sc0|sc1 */);
  }
}

// K=512 dual-N-tile 16x16x32 MFMA GEMM from role-major swizzled LDS.
// A-frag: row = lane&15, k = ks*32 + (lane>>4)*8 -> role = ks>>1,
// logical u = ((ks&1)<<2) + kc, phys u' = u ^ (row&7).
__device__ __forceinline__ void gemm16(const f16x8 (&wA)[16], const f16x8 (&wB)[16],
                                       const f16* lds, int lane,
                                       f32x4& acc0, f32x4& acc1) {
  const int r  = lane & 15;
  const int kc = lane >> 4;            // 0..3
  #pragma unroll
  for (int ks = 0; ks < 16; ++ks) {
    int role_k = ks >> 1;
    int u = ((ks & 1) << 2) + kc;
    int off = role_k * 2048 + r * 128 + ((u ^ (r & 7)) << 4);
    f16x8 a = *(const f16x8*)((const char*)lds + off);
    acc0 = __builtin_amdgcn_mfma_f32_16x16x32_f16(a, wA[ks], acc0, 0, 0, 0);
    acc1 = __builtin_amdgcn_mfma_f32_16x16x32_f16(a, wB[ks], acc1, 0, 0, 0);
  }
}

// 144 blocks x 512 threads (8 waves).
// bid 0..127: gates. grp = bid&15 owns batch rows [16g,16g+16); role = bid>>4
//             owns j-slice [64r,64r+64) x 4 gates.
// bid 128..143: out-projection block per group, lagging on a 4-slot ring.
// Flags: one 64-B line per flag — flags[(grp*9+r)*FSTRIDE] = steps done by
// block r (r=8: out block, posted right after its stage completes).
// INCREMENTAL STAGE: wave w's lane 0 polls flag w only (one poller per line
// per block) and stages stripe w immediately — early stripes overlap the
// straggler's wait; pre-stage barrier removed (3 barriers/step).
__global__ __launch_bounds__(512, 2) void lstm_persist(
    const f16* __restrict__ x0hi, const f16* __restrict__ x0lo,
    const f16* __restrict__ h0hi, const f16* __restrict__ h0lo,
    const float* __restrict__ c0,
    const f16* __restrict__ Wih16, const f16* __restrict__ Whh16,
    const f16* __restrict__ Wbig16, const f16* __restrict__ Wlin16,
    const float* __restrict__ bias0, const float* __restrict__ bias1,
    const float* __restrict__ b_lin,
    const float4* __restrict__ stepc,
    unsigned* __restrict__ X,                 // 4 slots x 16 grp x XSLOT_U32
    float* __restrict__ bh, float* __restrict__ bc,
    int* __restrict__ flags,
    float* __restrict__ outp)
{
  __shared__ f16 LdsA[8192];        // 16 KB: [role][16 rows][64 f16]
  __shared__ float gbuf[4096];      // 16 KB: [gate][m<16][64 j], col-swizzled

  const int tid  = threadIdx.x;
  const int lane = tid & 63;
  const int wv   = tid >> 6;            // wave 0..7
  const int bid  = blockIdx.x;
  const bool isG = bid < 128;
  const int grp  = isG ? (bid & 15) : (bid - 128);
  const int role = bid >> 4;            // gates only: 0..7
  const int b0   = grp * GR;
  const int r16  = lane & 15;
  const int kc   = lane >> 4;           // 0..3
  const int ksel = kc * 8;

  int* gflag = flags + grp * 9 * FSTRIDE;   // flag r at gflag[r*FSTRIDE]

  // ---- persistent W fragments: two 16-row N-tiles x K=512 -> 128 VGPR ----
  int rowA, rowB;
  const f16* wsrc;
  if (isG) {
    rowA = (wv & 3) * 512 + role * 64 + (wv >> 2) * 32 + r16;   // W_big row
    rowB = rowA + 16;
    wsrc = Wbig16;
  } else {
    rowA = wv * 32 + r16;                                       // W_lin row (d-col)
    rowB = rowA + 16;
    wsrc = Wlin16;
  }
  f16x8 wA[16], wB[16];
  #pragma unroll
  for (int ks = 0; ks < 16; ++ks) {
    wA[ks] = *(const f16x8*)(wsrc + (size_t)rowA * HH + ks * 32 + ksel);
    wB[ks] = *(const f16x8*)(wsrc + (size_t)rowB * HH + ks * 32 + ksel);
  }

  if (isG) {
    // ---- per-thread epilogue constants (2 cells/thread) ----
    int   eidx[2];
    float creg[2];
    const int jl = tid & 63;
    const int jg = role * 64 + jl;
    const float bI = bias1[jg],        bF = bias1[512 + jg];
    const float bG = bias1[1024 + jg], bO = bias1[1536 + jg];
    #pragma unroll
    for (int i = 0; i < 2; ++i) {
      int c = i * 512 + tid;
      int bl = c >> 6;                  // 0..15
      eidx[i] = (b0 + bl) * HH + jg;
      creg[i] = c0[eidx[i]];
    }

    for (int t = 0; t < TT; ++t) {
      // skip-buffer prefetch FIRST (latency hides under the flag spin)
      const float4 sc = stepc[t];
      const int pos = t & (SS - 1);
      float shv[2], scv[2];
      #pragma unroll
      for (int i = 0; i < 2; ++i) {
        int bx = pos * BH + eidx[i];
        shv[i] = bh[bx];
        scv[i] = bc[bx];
      }

      if (t > 0) {
        // wave w: lane 0 polls flag w (one poller per line per block);
        // wave 0 lane 1 guards X-slot ring reuse vs the out block.
        if (lane == 0) {
          while (__hip_atomic_load(&gflag[wv * FSTRIDE], __ATOMIC_RELAXED,
                                   __HIP_MEMORY_SCOPE_AGENT) < t) {}
        } else if (wv == 0 && lane == 1 && t >= 4) {
          while (__hip_atomic_load(&gflag[8 * FSTRIDE], __ATOMIC_RELAXED,
                                   __HIP_MEMORY_SCOPE_AGENT) < t - 3) {}
        }
        stage_stripe(X + (size_t)(((t - 1) & 3) * NGRP + grp) * XSLOT_U32,
                     wv, LdsA, lane);
      }

      f32x4 acc0, acc1;
      #pragma unroll
      for (int i = 0; i < 4; ++i) { acc0[i] = 0.f; acc1[i] = 0.f; }
      if (t == 0) {
        const f16* arh = x0hi + (size_t)(b0 + r16) * DD;
        const f16* arl = x0lo + (size_t)(b0 + r16) * DD;
        const f16* wap = Wih16 + (size_t)rowA * DD;
        const f16* wbp = Wih16 + (size_t)rowB * DD;
        #pragma unroll
        for (int ks = 0; ks < 8; ++ks) {          // K=256: x0 @ W_ih^T
          int ko = ks * 32 + ksel;
          f16x8 wa = *(const f16x8*)(wap + ko);
          f16x8 wb = *(const f16x8*)(wbp + ko);
          f16x8 ah = *(const f16x8*)(arh + ko);
          f16x8 al = *(const f16x8*)(arl + ko);
          acc0 = __builtin_amdgcn_mfma_f32_16x16x32_f16(ah, wa, acc0, 0, 0, 0);
          acc1 = __builtin_amdgcn_mfma_f32_16x16x32_f16(ah, wb, acc1, 0, 0, 0);
          acc0 = __builtin_amdgcn_mfma_f32_16x16x32_f16(al, wa, acc0, 0, 0, 0);
          acc1 = __builtin_amdgcn_mfma_f32_16x16x32_f16(al, wb, acc1, 0, 0, 0);
        }
        const f16* brh = h0hi + (size_t)(b0 + r16) * HH;
        const f16* brl = h0lo + (size_t)(b0 + r16) * HH;
        const f16* qap = Whh16 + (size_t)rowA * HH;
        const f16* qbp = Whh16 + (size_t)rowB * HH;
        #pragma unroll
        for (int ks = 0; ks < 16; ++ks) {         // K=512: h0 @ W_hh^T
          int ko = ks * 32 + ksel;
          f16x8 wa = *(const f16x8*)(qap + ko);
          f16x8 wb = *(const f16x8*)(qbp + ko);
          f16x8 ah = *(const f16x8*)(brh + ko);
          f16x8 al = *(const f16x8*)(brl + ko);
          acc0 = __builtin_amdgcn_mfma_f32_16x16x32_f16(ah, wa, acc0, 0, 0, 0);
          acc1 = __builtin_amdgcn_mfma_f32_16x16x32_f16(ah, wb, acc1, 0, 0, 0);
          acc0 = __builtin_amdgcn_mfma_f32_16x16x32_f16(al, wa, acc0, 0, 0, 0);
          acc1 = __builtin_amdgcn_mfma_f32_16x16x32_f16(al, wb, acc1, 0, 0, 0);
        }
        __syncthreads();                 // align with t>0 barrier count
      } else {
        __syncthreads();                 // all stripes staged (vmcnt drained)
        gemm16(wA, wB, LdsA, lane, acc0, acc1);
      }

      // acc -> gbuf [gate][m][64 j], column swizzled by +16*(m>>2)
      {
        const int g4 = wv & 3, jh = wv >> 2;
        #pragma unroll
        for (int rg = 0; rg < 4; ++rg) {
          int m  = kc * 4 + rg;
          int j0 = jh * 32 + r16;
          int cs0 = (j0      + 16 * kc) & 63;
          int cs1 = (j0 + 16 + 16 * kc) & 63;
          gbuf[g4 * 1024 + m * 64 + cs0] = acc0[rg];
          gbuf[g4 * 1024 + m * 64 + cs1] = acc1[rg];
        }
      }
      __syncthreads();

      // epilogue phase 1: gate math up to ch, publish X (role stripe), flag
      const float a1 = sc.x, a2 = sc.y, nrm = sc.z;
      float baI = bI, baF = bF, baG = bG, baO = bO;
      if (t == 0) {
        baI = bias0[jg];        baF = bias0[512 + jg];
        baG = bias0[1024 + jg]; baO = bias0[1536 + jg];
      }
      unsigned* Xw = X + (size_t)((t & 3) * NGRP + grp) * XSLOT_U32;
      float hnv[2], cnv[2], chv[2];
      #pragma unroll
      for (int i = 0; i < 2; ++i) {
        int c = i * 512 + tid;
        int bl = c >> 6;                           // m
        int jj = c & 63;
        int gofs = bl * 64 + ((jj + 16 * (bl >> 2)) & 63);
        float pi = gbuf[gofs]        + baI;
        float pf = gbuf[1024 + gofs] + baF;
        float pg = gbuf[2048 + gofs] + baG;
        float po = gbuf[3072 + gofs] + baO;
        float i_ = sigm(pi), f_ = sigm(pf), o_ = sigm(po), g_ = ftanh(pg);
        float cnew = fmaf(f_, creg[i], i_ * g_);
        float hnew = o_ * ftanh(cnew);
        float ch = (a1 * hnew + a2 * ftanh(shv[i])) * nrm;
        hnv[i] = hnew; cnv[i] = cnew; chv[i] = ch;
        f16 hv = (f16)ch;
        unsigned hb = (unsigned)*(const unsigned short*)&hv;
        unsigned part = (unsigned)__shfl_xor((int)hb, 1);
        if ((tid & 1) == 0)
          __hip_atomic_store(&Xw[role * 512 + bl * 32 + (jl >> 1)], hb | (part << 16),
                             __ATOMIC_RELAXED, __HIP_MEMORY_SCOPE_AGENT);
      }
      __syncthreads();                 // drains X stores of all waves (vmcnt 0)
      if (tid == 0)
        __hip_atomic_store(&gflag[role * FSTRIDE], t + 1, __ATOMIC_RELAXED,
                           __HIP_MEMORY_SCOPE_AGENT);

      // epilogue phase 2 (off critical path): cc, skip buffers, finals
      #pragma unroll
      for (int i = 0; i < 2; ++i) {
        float cc = (a1 * cnv[i] + a2 * ftanh(scv[i])) * nrm;
        creg[i] = cc;
        int bx = pos * BH + eidx[i];
        bh[bx] = hnv[i];
        bc[bx] = cnv[i];
        if (t == TT - 1) {
          __builtin_nontemporal_store(chv[i], &outp[OUT_BASE + eidx[i]]);       // h_fin
          __builtin_nontemporal_store(cc,     &outp[OUT_BASE + BH + eidx[i]]);  // c_fin
        }
      }
    }
  } else {
    // ---------- lagging out-projection block (one per group) ----------
    const float bld0 = b_lin[rowA];
    const float bld1 = b_lin[rowB];
    for (int s = 0; s < TT; ++s) {
      // wave w: lane 0 polls flag w, then stages stripe w immediately
      if (lane == 0) {
        while (__hip_atomic_load(&gflag[wv * FSTRIDE], __ATOMIC_RELAXED,
                                 __HIP_MEMORY_SCOPE_AGENT) < s + 1) {}
      }
      stage_stripe(X + (size_t)((s & 3) * NGRP + grp) * XSLOT_U32, wv, LdsA, lane);
      __syncthreads();                 // staging complete (vmcnt drained)
      if (tid == 0)                    // EARLY slot release: staged == consumed
        __hip_atomic_store(&gflag[8 * FSTRIDE], s + 1, __ATOMIC_RELAXED,
                           __HIP_MEMORY_SCOPE_AGENT);
      f32x4 acc0, acc1;
      #pragma unroll
      for (int i = 0; i < 4; ++i) { acc0[i] = 0.f; acc1[i] = 0.f; }
      gemm16(wA, wB, LdsA, lane, acc0, acc1);
      const size_t tbase = (size_t)s * DD + wv * 32 + r16;
      #pragma unroll
      for (int rg = 0; rg < 4; ++rg) {
        int m = kc * 4 + rg;
        __builtin_nontemporal_store(acc0[rg] + bld0,
                                    &outp[(size_t)(b0 + m) * (TT*DD) + tbase]);
        __builtin_nontemporal_store(acc1[rg] + bld1,
                                    &outp[(size_t)(b0 + m) * (TT*DD) + tbase + 16]);
      }
      __syncthreads();                 // all waves done reading LdsA before next stage
    }
  }
}

// ---------------- host launch ----------------

extern "C" void kernel_launch(void* const* d_in, const int* in_sizes, int n_in,
                              void* d_out, int out_size, void* d_ws, size_t ws_size,
                              hipStream_t stream)
{
  const float* x0    = (const float*)d_in[0];
  const float* h0    = (const float*)d_in[1];
  const float* c0    = (const float*)d_in[2];
  const float* W_ih  = (const float*)d_in[3];
  const float* W_hh  = (const float*)d_in[4];
  const float* b_ih  = (const float*)d_in[5];
  const float* b_hh  = (const float*)d_in[6];
  const float* W_lin = (const float*)d_in[7];
  const float* b_lin = (const float*)d_in[8];
  const int*   w1    = (const int*)d_in[9];
  const int*   w2    = (const int*)d_in[10];

  char* p = (char*)d_ws;
  f16* Wbig16 = (f16*)p;            p += (size_t)G4H*HH*2;
  f16* Wih16  = (f16*)p;            p += (size_t)G4H*DD*2;
  f16* Whh16  = (f16*)p;            p += (size_t)G4H*HH*2;
  f16* Wlin16 = (f16*)p;            p += (size_t)DD*HH*2;
  f16* x0hi   = (f16*)p;            p += (size_t)BB*DD*2;
  f16* x0lo   = (f16*)p;            p += (size_t)BB*DD*2;
  f16* h0hi   = (f16*)p;            p += (size_t)BH*2;
  f16* h0lo   = (f16*)p;            p += (size_t)BH*2;
  unsigned* X = (unsigned*)p;       p += (size_t)4*NGRP*XSLOT_U32*4;   // 1 MB
  float* bh   = (float*)p;          p += (size_t)SS*BH*4;
  float* bc   = (float*)p;          p += (size_t)SS*BH*4;
  float* bias0= (float*)p;          p += G4H*4;
  float* bias1= (float*)p;          p += G4H*4;
  float4* stepc = (float4*)p;       p += (size_t)TT*16;
  int*  flags = (int*)p;            p += 4096*4;
  float* outp = (float*)d_out;

  hipLaunchKernelGGL(prep_wbig16, dim3(32, 8), dim3(256), 0, stream,
                     W_ih, W_hh, W_lin, Wbig16);
  hipLaunchKernelGGL(prep_bias, dim3(8), dim3(256), 0, stream,
                     b_ih, b_hh, W_ih, b_lin, bias0, bias1);
  hipLaunchKernelGGL(prep_cvtw, dim3(6656), dim3(256), 0, stream,
                     W_ih, W_hh, W_lin, Wih16, Whh16, Wlin16);
  hipLaunchKernelGGL(prep_init, dim3(4096), dim3(256), 0, stream,
                     x0, h0, c0, w1, w2, bh, bc, x0hi, x0lo, h0hi, h0lo, stepc, flags);

  hipLaunchKernelGGL(lstm_persist, dim3(128 + NGRP), dim3(512), 0, stream,
                     x0hi, x0lo, h0hi, h0lo, c0, Wih16, Whh16, Wbig16, Wlin16,
                     bias0, bias1, b_lin, stepc, X, bh, bc, flags, outp);
}